// Round 2
// baseline (2483.421 us; speedup 1.0000x reference)
//
#include <hip/hip_runtime.h>
#include <hip/hip_bf16.h>

#define NN 100000
#define DD 128
#define MM 3
#define EE 1600000
#define ATT_H 128
#define NBLK 98  // ceil(NN/1024)

typedef unsigned int uint32_hip;

// ---- bf16 helpers (z stored as raw bf16 bits in ushort; pairs packed in uint) ----
__device__ __forceinline__ float bflo(uint32_hip u) { return __uint_as_float(u << 16); }
__device__ __forceinline__ float bfhi(uint32_hip u) { return __uint_as_float(u & 0xffff0000u); }
__device__ __forceinline__ unsigned short f2bf(float f) {
  union { __hip_bfloat16 b; unsigned short u; } cv;
  cv.b = __float2bfloat16(f);
  return cv.u;
}
__device__ __forceinline__ uint32_hip packbf2(float x, float y) {
  return (uint32_hip)f2bf(x) | ((uint32_hip)f2bf(y) << 16);
}

// ---------- CSR build ----------
__global__ void hist_kernel(const int* __restrict__ e0, const int* __restrict__ e1,
                            const int* __restrict__ e2, int* __restrict__ counts) {
  int tid = blockIdx.x * blockDim.x + threadIdx.x;
  int m = blockIdx.y;
  const int* ei = (m == 0) ? e0 : (m == 1) ? e1 : e2;
  if (tid < EE) {
    int d = ei[EE + tid];
    atomicAdd(&counts[m * NN + d], 1);
  }
}

__global__ void dinv_kernel(const int* __restrict__ counts, float* __restrict__ dinv) {
  int i = blockIdx.x * blockDim.x + threadIdx.x;
  if (i < MM * NN) dinv[i] = rsqrtf((float)(counts[i] + 1));  // +1 self loop
}

__global__ void scan1_kernel(const int* __restrict__ counts, int* __restrict__ offsets,
                             int* __restrict__ blocksums) {
  __shared__ int sdata[256];
  int m = blockIdx.y, b = blockIdx.x, t = threadIdx.x;
  int base = b * 1024 + t * 4;
  int v[4]; int sum = 0;
  for (int j = 0; j < 4; ++j) {
    int i = base + j;
    v[j] = (i < NN) ? counts[m * NN + i] : 0;
    sum += v[j];
  }
  sdata[t] = sum;
  __syncthreads();
  for (int off = 1; off < 256; off <<= 1) {
    int val = (t >= off) ? sdata[t - off] : 0;
    __syncthreads();
    sdata[t] += val;
    __syncthreads();
  }
  int excl = sdata[t] - sum;
  if (t == 255) blocksums[m * NBLK + b] = sdata[255];
  int run = excl;
  for (int j = 0; j < 4; ++j) {
    int i = base + j;
    if (i < NN) offsets[m * (NN + 1) + i] = run;
    run += v[j];
  }
}

__global__ void scan2_kernel(int* __restrict__ blocksums) {
  __shared__ int s[128];
  int m = blockIdx.x, t = threadIdx.x;
  int v = (t < NBLK) ? blocksums[m * NBLK + t] : 0;
  s[t] = v;
  __syncthreads();
  for (int off = 1; off < 128; off <<= 1) {
    int val = (t >= off) ? s[t - off] : 0;
    __syncthreads();
    s[t] += val;
    __syncthreads();
  }
  if (t < NBLK) blocksums[m * NBLK + t] = s[t] - v;  // exclusive
}

__global__ void scan3_kernel(int* __restrict__ offsets, const int* __restrict__ blocksums,
                             int* __restrict__ cursor) {
  int m = blockIdx.y;
  int i = blockIdx.x * 256 + threadIdx.x;
  if (i < NN) {
    int o = offsets[m * (NN + 1) + i] + blocksums[m * NBLK + (i >> 10)];
    offsets[m * (NN + 1) + i] = o;
    cursor[m * NN + i] = o;
  }
  if (i == NN) offsets[m * (NN + 1) + NN] = EE;
}

__global__ void scatter_kernel(const int* __restrict__ e0, const int* __restrict__ e1,
                               const int* __restrict__ e2, int* __restrict__ cursor,
                               int* __restrict__ csr_src) {
  int tid = blockIdx.x * blockDim.x + threadIdx.x;
  int m = blockIdx.y;
  const int* ei = (m == 0) ? e0 : (m == 1) ? e1 : e2;
  if (tid < EE) {
    int s = ei[tid];
    int d = ei[EE + tid];
    int pos = atomicAdd(&cursor[m * NN + d], 1);
    csr_src[(size_t)m * EE + pos] = s;
  }
}

// ---------- embedding gather: h (fp32) lives in d_out ----------
__global__ void embed_kernel(const int* __restrict__ x, const float* __restrict__ tbl,
                             float* __restrict__ h) {
  int i = blockIdx.x * 256 + threadIdx.x;
  if (i < NN * (DD / 4)) {
    int n = i >> 5;  // 32 float4 per row
    int c = i & 31;
    ((float4*)h)[i] = ((const float4*)tbl)[(size_t)x[n] * 32 + c];
  }
}

// ---------- normalized aggregation -> bf16 z[m] ----------
__global__ void agg_kernel(const float* __restrict__ h, const float* __restrict__ dinv_m,
                           const int* __restrict__ offsets_m, const int* __restrict__ csr_src_m,
                           unsigned short* __restrict__ zout) {
  int gtid = blockIdx.x * blockDim.x + threadIdx.x;
  int n = gtid >> 6;
  int lane = gtid & 63;
  if (n >= NN) return;
  const float2* h2 = (const float2*)h;
  float di = dinv_m[n];
  float2 hv = h2[(size_t)n * 64 + lane];
  float ax = di * hv.x, ay = di * hv.y;
  int beg = offsets_m[n], end = offsets_m[n + 1];
  for (int e = beg; e < end; ++e) {
    int s = csr_src_m[e];
    float ns = dinv_m[s];
    float2 hs = h2[(size_t)s * 64 + lane];
    ax = fmaf(ns, hs.x, ax);
    ay = fmaf(ns, hs.y, ay);
  }
  ((uint32_hip*)zout)[(size_t)n * 64 + lane] = packbf2(ax * di, ay * di);
}

// ---------- in-place GEMM on bf16 z: Z <- Z @ W + bias (fp32 math) ----------
// LDS: 32KB (W k-half) + 8.4KB (A tile) = 41.2KB; 16 rows/block, 4 waves
__global__ void gemm_bias_kernel(unsigned short* __restrict__ Z, const float* __restrict__ Wmat,
                                 const float* __restrict__ bias, int R) {
  __shared__ float Ws[64 * 128];
  __shared__ float As[16 * 132];
  int t = threadIdx.x;
  int wid = t >> 6, lane = t & 63;
  int row0 = blockIdx.x * 16;
  const uint32_hip* Zu = (const uint32_hip*)Z;
#pragma unroll
  for (int i = 0; i < 4; ++i) {
    int idx = t + 256 * i;       // 0..1023
    int r = idx >> 6, c2 = idx & 63;
    int grow = row0 + r;
    uint32_hip bits = (grow < R) ? Zu[(size_t)grow * 64 + c2] : 0u;
    *(float2*)&As[r * 132 + c2 * 2] = make_float2(bflo(bits), bfhi(bits));
  }
  int c0 = lane * 2;
  int myr = wid * 4;
  float acc[4][2] = {{0.f, 0.f}, {0.f, 0.f}, {0.f, 0.f}, {0.f, 0.f}};
  const float4* W4 = (const float4*)Wmat;
  float4* Ws4 = (float4*)Ws;
  for (int half = 0; half < 2; ++half) {
    __syncthreads();  // As ready (pass 0) / Ws reuse safe (pass 1)
#pragma unroll
    for (int i = 0; i < 8; ++i) Ws4[t + 256 * i] = W4[half * 2048 + t + 256 * i];
    __syncthreads();
    int kb = half * 64;
    for (int k = 0; k < 64; k += 4) {
      float4 a0 = *(const float4*)&As[(myr + 0) * 132 + kb + k];
      float4 a1 = *(const float4*)&As[(myr + 1) * 132 + kb + k];
      float4 a2 = *(const float4*)&As[(myr + 2) * 132 + kb + k];
      float4 a3 = *(const float4*)&As[(myr + 3) * 132 + kb + k];
#pragma unroll
      for (int kk = 0; kk < 4; ++kk) {
        float2 w = *(const float2*)&Ws[(k + kk) * 128 + c0];
        float av0 = ((const float*)&a0)[kk];
        float av1 = ((const float*)&a1)[kk];
        float av2 = ((const float*)&a2)[kk];
        float av3 = ((const float*)&a3)[kk];
        acc[0][0] = fmaf(av0, w.x, acc[0][0]); acc[0][1] = fmaf(av0, w.y, acc[0][1]);
        acc[1][0] = fmaf(av1, w.x, acc[1][0]); acc[1][1] = fmaf(av1, w.y, acc[1][1]);
        acc[2][0] = fmaf(av2, w.x, acc[2][0]); acc[2][1] = fmaf(av2, w.y, acc[2][1]);
        acc[3][0] = fmaf(av3, w.x, acc[3][0]); acc[3][1] = fmaf(av3, w.y, acc[3][1]);
      }
    }
  }
  float2 b2 = *(const float2*)&bias[c0];
#pragma unroll
  for (int i = 0; i < 4; ++i) {
    int grow = row0 + myr + i;
    if (grow < R)
      ((uint32_hip*)Z)[(size_t)grow * 64 + lane] = packbf2(acc[i][0] + b2.x, acc[i][1] + b2.y);
  }
}

// ---------- fused semantic attention score: w[r] = tanh(Z[r]@W1 + b1) . w2 ----------
__global__ void att_kernel(const unsigned short* __restrict__ Zin, const float* __restrict__ W1,
                           const float* __restrict__ b1, const float* __restrict__ w2,
                           float* __restrict__ wout, int R) {
  __shared__ float Ws[64 * 128];
  __shared__ float As[16 * 132];
  int t = threadIdx.x;
  int wid = t >> 6, lane = t & 63;
  int row0 = blockIdx.x * 16;
  const uint32_hip* Zu = (const uint32_hip*)Zin;
#pragma unroll
  for (int i = 0; i < 4; ++i) {
    int idx = t + 256 * i;
    int r = idx >> 6, c2 = idx & 63;
    int grow = row0 + r;
    uint32_hip bits = (grow < R) ? Zu[(size_t)grow * 64 + c2] : 0u;
    *(float2*)&As[r * 132 + c2 * 2] = make_float2(bflo(bits), bfhi(bits));
  }
  int c0 = lane * 2;
  int myr = wid * 4;
  float acc[4][2] = {{0.f, 0.f}, {0.f, 0.f}, {0.f, 0.f}, {0.f, 0.f}};
  const float4* W4 = (const float4*)W1;
  float4* Ws4 = (float4*)Ws;
  for (int half = 0; half < 2; ++half) {
    __syncthreads();
#pragma unroll
    for (int i = 0; i < 8; ++i) Ws4[t + 256 * i] = W4[half * 2048 + t + 256 * i];
    __syncthreads();
    int kb = half * 64;
    for (int k = 0; k < 64; k += 4) {
      float4 a0 = *(const float4*)&As[(myr + 0) * 132 + kb + k];
      float4 a1 = *(const float4*)&As[(myr + 1) * 132 + kb + k];
      float4 a2 = *(const float4*)&As[(myr + 2) * 132 + kb + k];
      float4 a3 = *(const float4*)&As[(myr + 3) * 132 + kb + k];
#pragma unroll
      for (int kk = 0; kk < 4; ++kk) {
        float2 w = *(const float2*)&Ws[(k + kk) * 128 + c0];
        float av0 = ((const float*)&a0)[kk];
        float av1 = ((const float*)&a1)[kk];
        float av2 = ((const float*)&a2)[kk];
        float av3 = ((const float*)&a3)[kk];
        acc[0][0] = fmaf(av0, w.x, acc[0][0]); acc[0][1] = fmaf(av0, w.y, acc[0][1]);
        acc[1][0] = fmaf(av1, w.x, acc[1][0]); acc[1][1] = fmaf(av1, w.y, acc[1][1]);
        acc[2][0] = fmaf(av2, w.x, acc[2][0]); acc[2][1] = fmaf(av2, w.y, acc[2][1]);
        acc[3][0] = fmaf(av3, w.x, acc[3][0]); acc[3][1] = fmaf(av3, w.y, acc[3][1]);
      }
    }
  }
  float2 b2 = *(const float2*)&b1[c0];
  float2 w22 = *(const float2*)&w2[c0];
#pragma unroll
  for (int i = 0; i < 4; ++i) {
    float pv = tanhf(acc[i][0] + b2.x) * w22.x + tanhf(acc[i][1] + b2.y) * w22.y;
#pragma unroll
    for (int off = 32; off > 0; off >>= 1) pv += __shfl_down(pv, off);
    if (lane == 0) {
      int grow = row0 + myr + i;
      if (grow < R) wout[grow] = pv;
    }
  }
}

// ---------- softmax over M + weighted sum (+ final log_softmax) ----------
__global__ void combine_kernel(const unsigned short* __restrict__ Z, const float* __restrict__ wbuf,
                               float* __restrict__ hout, int last) {
  int gtid = blockIdx.x * blockDim.x + threadIdx.x;
  int n = gtid >> 6, lane = gtid & 63;
  if (n >= NN) return;
  float w0 = wbuf[n], w1 = wbuf[NN + n], w2v = wbuf[2 * NN + n];
  float mx = fmaxf(w0, fmaxf(w1, w2v));
  float ee0 = expf(w0 - mx), ee1 = expf(w1 - mx), ee2 = expf(w2v - mx);
  float inv = 1.0f / (ee0 + ee1 + ee2);
  float bb0 = ee0 * inv, bb1 = ee1 * inv, bb2 = ee2 * inv;
  const uint32_hip* Zu = (const uint32_hip*)Z;
  size_t base = (size_t)n * 64 + lane;
  uint32_hip p0 = Zu[base];
  uint32_hip p1 = Zu[(size_t)NN * 64 + base];
  uint32_hip p2 = Zu[(size_t)2 * NN * 64 + base];
  float ox = bb0 * bflo(p0) + bb1 * bflo(p1) + bb2 * bflo(p2);
  float oy = bb0 * bfhi(p0) + bb1 * bfhi(p1) + bb2 * bfhi(p2);
  if (!last) {
    ((float2*)hout)[base] = make_float2(ox, oy);
  } else {
    float mxv = fmaxf(ox, oy);
#pragma unroll
    for (int off = 32; off > 0; off >>= 1) mxv = fmaxf(mxv, __shfl_xor(mxv, off));
    float s = expf(ox - mxv) + expf(oy - mxv);
#pragma unroll
    for (int off = 32; off > 0; off >>= 1) s += __shfl_xor(s, off);
    float lse = mxv + logf(s);
    ((float2*)hout)[base] = make_float2(ox - lse, oy - lse);
  }
}

extern "C" void kernel_launch(void* const* d_in, const int* in_sizes, int n_in,
                              void* d_out, int out_size, void* d_ws, size_t ws_size,
                              hipStream_t stream) {
  const int* x = (const int*)d_in[0];
  const int* e0 = (const int*)d_in[1];
  const int* e1 = (const int*)d_in[2];
  const int* e2 = (const int*)d_in[3];
  const float* embed = (const float*)d_in[4];
  const float* W = (const float*)d_in[5];    // [2][3][128][128]
  const float* B = (const float*)d_in[6];    // [2][3][128]
  const float* aw1 = (const float*)d_in[7];  // [2][128][128]
  const float* ab1 = (const float*)d_in[8];  // [2][128]
  const float* aw2 = (const float*)d_in[9];  // [2][128]
  float* out = (float*)d_out;
  float* h = out;  // h (fp32, N*D == out_size) lives in d_out until final combine

  char* ws = (char*)d_ws;
  size_t off = 0;
  auto alloc = [&](size_t bytes) {
    void* p = ws + off;
    off += (bytes + 255) & ~(size_t)255;
    return p;
  };
  unsigned short* z = (unsigned short*)alloc((size_t)MM * NN * DD * 2);  // bf16, 76.8 MB
  int* csr = (int*)alloc((size_t)MM * EE * 4);                           // 19.2 MB
  int* counts = (int*)alloc((size_t)MM * NN * 4);
  int* offs = (int*)alloc((size_t)MM * (NN + 1) * 4);
  int* cursor = (int*)alloc((size_t)MM * NN * 4);
  float* dinv = (float*)alloc((size_t)MM * NN * 4);
  float* wbuf = (float*)alloc((size_t)MM * NN * 4);
  int* bsums = (int*)alloc((size_t)MM * NBLK * 4);
  // total ~102 MB

  hipMemsetAsync(counts, 0, (size_t)MM * NN * 4, stream);

  dim3 bs(256);
  hist_kernel<<<dim3((EE + 255) / 256, 3), bs, 0, stream>>>(e0, e1, e2, counts);
  dinv_kernel<<<dim3((MM * NN + 255) / 256), bs, 0, stream>>>(counts, dinv);
  scan1_kernel<<<dim3(NBLK, 3), bs, 0, stream>>>(counts, offs, bsums);
  scan2_kernel<<<dim3(3), dim3(128), 0, stream>>>(bsums);
  scan3_kernel<<<dim3((NN + 256) / 256, 3), bs, 0, stream>>>(offs, bsums, cursor);
  scatter_kernel<<<dim3((EE + 255) / 256, 3), bs, 0, stream>>>(e0, e1, e2, cursor, csr);
  embed_kernel<<<dim3((NN * 32 + 255) / 256), bs, 0, stream>>>(x, embed, h);

  for (int l = 0; l < 2; ++l) {
    for (int m = 0; m < 3; ++m) {
      agg_kernel<<<dim3((NN + 3) / 4), bs, 0, stream>>>(
          h, dinv + m * NN, offs + m * (NN + 1), csr + (size_t)m * EE,
          z + (size_t)m * NN * DD);
      gemm_bias_kernel<<<dim3(NN / 16), bs, 0, stream>>>(
          z + (size_t)m * NN * DD, W + ((size_t)l * 3 + m) * DD * DD,
          B + ((size_t)l * 3 + m) * DD, NN);
    }
    att_kernel<<<dim3(3 * NN / 16), bs, 0, stream>>>(
        z, aw1 + (size_t)l * DD * ATT_H, ab1 + (size_t)l * ATT_H,
        aw2 + (size_t)l * ATT_H, wbuf, 3 * NN);
    combine_kernel<<<dim3((NN + 3) / 4), bs, 0, stream>>>(z, wbuf, (l == 1) ? out : h, l == 1);
  }
}

// Round 3
// 1991.615 us; speedup vs baseline: 1.2469x; 1.2469x over previous
//
#include <hip/hip_runtime.h>
#include <hip/hip_bf16.h>

#define NN 100000
#define DD 128
#define MM 3
#define EE 1600000
#define NBLK 98              // ceil(NN/1024) for scan
#define NBUK ((NN + 127) / 128)  // 782 dst-buckets per meta-path

typedef unsigned int uint32_hip;
typedef short short8 __attribute__((ext_vector_type(8)));
typedef float floatx4 __attribute__((ext_vector_type(4)));

// ---- bf16 helpers (pairs packed in uint) ----
__device__ __forceinline__ float bflo(uint32_hip u) { return __uint_as_float(u << 16); }
__device__ __forceinline__ float bfhi(uint32_hip u) { return __uint_as_float(u & 0xffff0000u); }
__device__ __forceinline__ unsigned short f2bf(float f) {
  union { __hip_bfloat16 b; unsigned short u; } cv;
  cv.b = __float2bfloat16(f);
  return cv.u;
}
__device__ __forceinline__ uint32_hip packbf2(float x, float y) {
  return (uint32_hip)f2bf(x) | ((uint32_hip)f2bf(y) << 16);
}
__device__ __forceinline__ float tanh_apx(float x) {
  float e = __expf(2.0f * x);
  return 1.0f - 2.0f / (e + 1.0f);
}

// ---------- per-node degree histogram ----------
__global__ void hist_kernel(const int* __restrict__ e0, const int* __restrict__ e1,
                            const int* __restrict__ e2, int* __restrict__ counts) {
  int tid = blockIdx.x * blockDim.x + threadIdx.x;
  int m = blockIdx.y;
  const int* ei = (m == 0) ? e0 : (m == 1) ? e1 : e2;
  if (tid < EE) {
    int d = ei[EE + tid];
    atomicAdd(&counts[m * NN + d], 1);
  }
}

__global__ void dinv_kernel(const int* __restrict__ counts, float* __restrict__ dinv) {
  int i = blockIdx.x * blockDim.x + threadIdx.x;
  if (i < MM * NN) dinv[i] = rsqrtf((float)(counts[i] + 1));  // +1 self loop
}

// ---------- scan (counts -> exclusive offsets) ----------
__global__ void scan1_kernel(const int* __restrict__ counts, int* __restrict__ offsets,
                             int* __restrict__ blocksums) {
  __shared__ int sdata[256];
  int m = blockIdx.y, b = blockIdx.x, t = threadIdx.x;
  int base = b * 1024 + t * 4;
  int v[4]; int sum = 0;
  for (int j = 0; j < 4; ++j) {
    int i = base + j;
    v[j] = (i < NN) ? counts[m * NN + i] : 0;
    sum += v[j];
  }
  sdata[t] = sum;
  __syncthreads();
  for (int off = 1; off < 256; off <<= 1) {
    int val = (t >= off) ? sdata[t - off] : 0;
    __syncthreads();
    sdata[t] += val;
    __syncthreads();
  }
  int excl = sdata[t] - sum;
  if (t == 255) blocksums[m * NBLK + b] = sdata[255];
  int run = excl;
  for (int j = 0; j < 4; ++j) {
    int i = base + j;
    if (i < NN) offsets[m * (NN + 1) + i] = run;
    run += v[j];
  }
}

__global__ void scan2_kernel(int* __restrict__ blocksums) {
  __shared__ int s[128];
  int m = blockIdx.x, t = threadIdx.x;
  int v = (t < NBLK) ? blocksums[m * NBLK + t] : 0;
  s[t] = v;
  __syncthreads();
  for (int off = 1; off < 128; off <<= 1) {
    int val = (t >= off) ? s[t - off] : 0;
    __syncthreads();
    s[t] += val;
    __syncthreads();
  }
  if (t < NBLK) blocksums[m * NBLK + t] = s[t] - v;  // exclusive
}

// finalize offsets; also init per-bucket cursors (bucket = 128 consecutive dst nodes)
__global__ void scan3_kernel(int* __restrict__ offsets, const int* __restrict__ blocksums,
                             int* __restrict__ bcur) {
  int m = blockIdx.y;
  int i = blockIdx.x * 256 + threadIdx.x;
  if (i < NN) {
    int o = offsets[m * (NN + 1) + i] + blocksums[m * NBLK + (i >> 10)];
    offsets[m * (NN + 1) + i] = o;
    if ((i & 127) == 0) bcur[m * NBUK + (i >> 7)] = o;
  }
  if (i == NN) offsets[m * (NN + 1) + NN] = EE;
}

// ---------- phase 1: partition edges into dst-buckets (packed src|dlow<<17) ----------
__global__ void partition_kernel(const int* __restrict__ e0, const int* __restrict__ e1,
                                 const int* __restrict__ e2, int* __restrict__ bcur,
                                 uint32_hip* __restrict__ ebuf) {
  int tid = blockIdx.x * blockDim.x + threadIdx.x;
  int m = blockIdx.y;
  const int* ei = (m == 0) ? e0 : (m == 1) ? e1 : e2;
  if (tid < EE) {
    int s = ei[tid];
    int d = ei[EE + tid];
    int pos = atomicAdd(&bcur[m * NBUK + (d >> 7)], 1);
    ebuf[(size_t)m * EE + pos] = (uint32_hip)s | ((uint32_hip)(d & 127) << 17);
  }
}

// ---------- phase 2: per-bucket LDS-cursor scatter into final CSR ----------
__global__ void bucket_sort_kernel(const uint32_hip* __restrict__ ebuf,
                                   const int* __restrict__ offsets, int* __restrict__ csr) {
  __shared__ int cur[128];
  int m = blockIdx.y, b = blockIdx.x, t = threadIdx.x;
  int node0 = b * 128;
  if (t < 128) {
    int nd = node0 + t;
    if (nd < NN) cur[t] = offsets[m * (NN + 1) + nd];
  }
  __syncthreads();
  int hi = min(node0 + 128, NN);
  int beg = offsets[m * (NN + 1) + node0];
  int end = offsets[m * (NN + 1) + hi];
  const uint32_hip* eb = ebuf + (size_t)m * EE;
  int* cs = csr + (size_t)m * EE;
  for (int e = beg + t; e < end; e += 256) {
    uint32_hip p = eb[e];
    int src = (int)(p & 0x1FFFFu);
    int dl = (int)(p >> 17);
    int pos = atomicAdd(&cur[dl], 1);
    cs[pos] = src;
  }
}

// ---------- embedding gather -> bf16 h (lives in d_out) ----------
__global__ void embed_kernel(const int* __restrict__ x, const float* __restrict__ tbl,
                             uint32_hip* __restrict__ hb) {
  int i = blockIdx.x * 256 + threadIdx.x;
  if (i < NN * 64) {
    int n = i >> 6;  // 64 uint (=bf16 pairs) per row
    int c = i & 63;
    float2 v = ((const float2*)tbl)[(size_t)x[n] * 64 + c];
    hb[i] = packbf2(v.x, v.y);
  }
}

// ---------- normalized aggregation (bf16 h -> bf16 z), one wave/node ----------
__global__ void agg_kernel(const uint32_hip* __restrict__ h, const float* __restrict__ dinv_m,
                           const int* __restrict__ offs_m, const int* __restrict__ csr_m,
                           uint32_hip* __restrict__ zout) {
  int gtid = blockIdx.x * blockDim.x + threadIdx.x;
  int n = gtid >> 6;
  int lane = gtid & 63;
  if (n >= NN) return;
  float di = dinv_m[n];
  uint32_hip u = h[(size_t)n * 64 + lane];
  float ax = di * bflo(u), ay = di * bfhi(u);
  int e = offs_m[n], end = offs_m[n + 1];
  for (; e + 4 <= end; e += 4) {
    int s0 = csr_m[e], s1 = csr_m[e + 1], s2 = csr_m[e + 2], s3 = csr_m[e + 3];
    float n0 = dinv_m[s0], n1 = dinv_m[s1], n2 = dinv_m[s2], n3 = dinv_m[s3];
    uint32_hip u0 = h[(size_t)s0 * 64 + lane];
    uint32_hip u1 = h[(size_t)s1 * 64 + lane];
    uint32_hip u2 = h[(size_t)s2 * 64 + lane];
    uint32_hip u3 = h[(size_t)s3 * 64 + lane];
    ax = fmaf(n0, bflo(u0), ax); ay = fmaf(n0, bfhi(u0), ay);
    ax = fmaf(n1, bflo(u1), ax); ay = fmaf(n1, bfhi(u1), ay);
    ax = fmaf(n2, bflo(u2), ax); ay = fmaf(n2, bfhi(u2), ay);
    ax = fmaf(n3, bflo(u3), ax); ay = fmaf(n3, bfhi(u3), ay);
  }
  for (; e < end; ++e) {
    int s = csr_m[e];
    float ns = dinv_m[s];
    uint32_hip us = h[(size_t)s * 64 + lane];
    ax = fmaf(ns, bflo(us), ax); ay = fmaf(ns, bfhi(us), ay);
  }
  zout[(size_t)n * 64 + lane] = packbf2(ax * di, ay * di);
}

// ---------- MFMA bf16 GEMM, in-place: Z <- Z @ W + bias ----------
// block = 256 thr = 4 waves, 64 rows/block (16/wave). W fp32 -> bf16 LDS, transposed,
// row stride 136 (bank-conflict-free b128 reads). A frags loaded directly from global z.
// 16x16x32 layouts (m89/m91): A[m=lane&15][k=quad*8+j]; B[k=quad*8+j][n=lane&15];
// C col=lane&15, row=quad*4+reg.
__global__ __launch_bounds__(256) void mfma_gemm_kernel(unsigned short* __restrict__ Z,
                                                        const float* __restrict__ Wmat,
                                                        const float* __restrict__ bias, int R) {
  __shared__ unsigned short Wt[128 * 136];
  int t = threadIdx.x;
  {
    uint32_hip* Wt_u = (uint32_hip*)Wt;
#pragma unroll
    for (int i = 0; i < 32; ++i) {
      int idx = i * 256 + t;  // 0..8191
      int k2 = idx >> 7;      // k pair index 0..63
      int nn = idx & 127;     // col
      float w0 = Wmat[(2 * k2) * 128 + nn];
      float w1 = Wmat[(2 * k2 + 1) * 128 + nn];
      Wt_u[nn * 68 + k2] = packbf2(w0, w1);
    }
  }
  __syncthreads();
  int wave = t >> 6, lane = t & 63;
  int quad = lane >> 4, ln = lane & 15;
  int rowbase = blockIdx.x * 64 + wave * 16;
  int arow = rowbase + ln;
  int arowc = (arow < R) ? arow : (R - 1);
  const short8* zrow = (const short8*)(Z + (size_t)arowc * 128);
  floatx4 acc[8];
#pragma unroll
  for (int c = 0; c < 8; ++c) acc[c] = (floatx4){0.f, 0.f, 0.f, 0.f};
#pragma unroll
  for (int kt = 0; kt < 4; ++kt) {
    short8 a = zrow[kt * 4 + quad];
#pragma unroll
    for (int c = 0; c < 8; ++c) {
      const short8* bp = (const short8*)(Wt + (c * 16 + ln) * 136 + kt * 32 + quad * 8);
      acc[c] = __builtin_amdgcn_mfma_f32_16x16x32_bf16(a, *bp, acc[c], 0, 0, 0);
    }
  }
#pragma unroll
  for (int c = 0; c < 8; ++c) {
    int col = c * 16 + ln;
    float bs = bias[col];
#pragma unroll
    for (int r = 0; r < 4; ++r) {
      int grow = rowbase + quad * 4 + r;
      if (grow < R) Z[(size_t)grow * 128 + col] = f2bf(acc[c][r] + bs);
    }
  }
}

// ---------- MFMA semantic attention score: w[r] = tanh(Z[r]@W1 + b1) . w2 ----------
__global__ __launch_bounds__(256) void mfma_att_kernel(const unsigned short* __restrict__ Z,
                                                       const float* __restrict__ W1,
                                                       const float* __restrict__ b1,
                                                       const float* __restrict__ w2,
                                                       float* __restrict__ wout, int R) {
  __shared__ unsigned short Wt[128 * 136];
  int t = threadIdx.x;
  {
    uint32_hip* Wt_u = (uint32_hip*)Wt;
#pragma unroll
    for (int i = 0; i < 32; ++i) {
      int idx = i * 256 + t;
      int k2 = idx >> 7;
      int nn = idx & 127;
      float w0 = W1[(2 * k2) * 128 + nn];
      float w1 = W1[(2 * k2 + 1) * 128 + nn];
      Wt_u[nn * 68 + k2] = packbf2(w0, w1);
    }
  }
  __syncthreads();
  int wave = t >> 6, lane = t & 63;
  int quad = lane >> 4, ln = lane & 15;
  int rowbase = blockIdx.x * 64 + wave * 16;
  int arow = rowbase + ln;
  int arowc = (arow < R) ? arow : (R - 1);
  const short8* zrow = (const short8*)(Z + (size_t)arowc * 128);
  floatx4 acc[8];
#pragma unroll
  for (int c = 0; c < 8; ++c) acc[c] = (floatx4){0.f, 0.f, 0.f, 0.f};
#pragma unroll
  for (int kt = 0; kt < 4; ++kt) {
    short8 a = zrow[kt * 4 + quad];
#pragma unroll
    for (int c = 0; c < 8; ++c) {
      const short8* bp = (const short8*)(Wt + (c * 16 + ln) * 136 + kt * 32 + quad * 8);
      acc[c] = __builtin_amdgcn_mfma_f32_16x16x32_bf16(a, *bp, acc[c], 0, 0, 0);
    }
  }
  float rows[4] = {0.f, 0.f, 0.f, 0.f};
#pragma unroll
  for (int c = 0; c < 8; ++c) {
    int col = c * 16 + ln;
    float bb = b1[col];
    float ww = w2[col];
#pragma unroll
    for (int r = 0; r < 4; ++r) rows[r] += tanh_apx(acc[c][r] + bb) * ww;
  }
#pragma unroll
  for (int off = 8; off > 0; off >>= 1) {
#pragma unroll
    for (int r = 0; r < 4; ++r) rows[r] += __shfl_down(rows[r], off);
  }
  if (ln == 0) {
#pragma unroll
    for (int r = 0; r < 4; ++r) {
      int grow = rowbase + quad * 4 + r;
      if (grow < R) wout[grow] = rows[r];
    }
  }
}

// ---------- softmax over M + weighted sum; layer0 -> bf16 h, layer1 -> fp32 log_softmax ----------
__global__ void combine_kernel(const unsigned short* __restrict__ Z,
                               const float* __restrict__ wbuf, uint32_hip* __restrict__ hb,
                               float* __restrict__ fout, int last) {
  int gtid = blockIdx.x * blockDim.x + threadIdx.x;
  int n = gtid >> 6, lane = gtid & 63;
  if (n >= NN) return;
  float w0 = wbuf[n], w1 = wbuf[NN + n], w2v = wbuf[2 * NN + n];
  float mx = fmaxf(w0, fmaxf(w1, w2v));
  float ee0 = __expf(w0 - mx), ee1 = __expf(w1 - mx), ee2 = __expf(w2v - mx);
  float inv = 1.0f / (ee0 + ee1 + ee2);
  float bb0 = ee0 * inv, bb1 = ee1 * inv, bb2 = ee2 * inv;
  const uint32_hip* Zu = (const uint32_hip*)Z;
  size_t base = (size_t)n * 64 + lane;
  uint32_hip p0 = Zu[base];
  uint32_hip p1 = Zu[(size_t)NN * 64 + base];
  uint32_hip p2 = Zu[(size_t)2 * NN * 64 + base];
  float ox = bb0 * bflo(p0) + bb1 * bflo(p1) + bb2 * bflo(p2);
  float oy = bb0 * bfhi(p0) + bb1 * bfhi(p1) + bb2 * bfhi(p2);
  if (!last) {
    hb[base] = packbf2(ox, oy);
  } else {
    float mxv = fmaxf(ox, oy);
#pragma unroll
    for (int off = 32; off > 0; off >>= 1) mxv = fmaxf(mxv, __shfl_xor(mxv, off));
    float s = __expf(ox - mxv) + __expf(oy - mxv);
#pragma unroll
    for (int off = 32; off > 0; off >>= 1) s += __shfl_xor(s, off);
    float lse = mxv + logf(s);
    ((float2*)fout)[base] = make_float2(ox - lse, oy - lse);
  }
}

extern "C" void kernel_launch(void* const* d_in, const int* in_sizes, int n_in,
                              void* d_out, int out_size, void* d_ws, size_t ws_size,
                              hipStream_t stream) {
  const int* x = (const int*)d_in[0];
  const int* e0 = (const int*)d_in[1];
  const int* e1 = (const int*)d_in[2];
  const int* e2 = (const int*)d_in[3];
  const float* embed = (const float*)d_in[4];
  const float* W = (const float*)d_in[5];    // [2][3][128][128]
  const float* B = (const float*)d_in[6];    // [2][3][128]
  const float* aw1 = (const float*)d_in[7];  // [2][128][128]
  const float* ab1 = (const float*)d_in[8];  // [2][128]
  const float* aw2 = (const float*)d_in[9];  // [2][128]
  float* out = (float*)d_out;
  uint32_hip* hb = (uint32_hip*)d_out;  // bf16 h (25.6MB) lives in d_out until final combine

  char* ws = (char*)d_ws;
  size_t off = 0;
  auto alloc = [&](size_t bytes) {
    void* p = ws + off;
    off += (bytes + 255) & ~(size_t)255;
    return p;
  };
  unsigned short* z = (unsigned short*)alloc((size_t)MM * NN * DD * 2);  // bf16, 76.8 MB
  int* csr = (int*)alloc((size_t)MM * EE * 4);                           // 19.2 MB
  int* counts = (int*)alloc((size_t)MM * NN * 4);
  int* offs = (int*)alloc((size_t)MM * (NN + 1) * 4);
  int* bcur = (int*)alloc((size_t)MM * NBUK * 4);
  float* dinv = (float*)alloc((size_t)MM * NN * 4);
  float* wbuf = (float*)alloc((size_t)MM * NN * 4);
  int* bsums = (int*)alloc((size_t)MM * NBLK * 4);
  // ebuf (bucket-partitioned packed edges, 19.2MB) aliases z: z is only written later (agg)
  uint32_hip* ebuf = (uint32_hip*)z;

  hipMemsetAsync(counts, 0, (size_t)MM * NN * 4, stream);

  dim3 bs(256);
  hist_kernel<<<dim3((EE + 255) / 256, 3), bs, 0, stream>>>(e0, e1, e2, counts);
  dinv_kernel<<<dim3((MM * NN + 255) / 256), bs, 0, stream>>>(counts, dinv);
  scan1_kernel<<<dim3(NBLK, 3), bs, 0, stream>>>(counts, offs, bsums);
  scan2_kernel<<<dim3(3), dim3(128), 0, stream>>>(bsums);
  scan3_kernel<<<dim3((NN + 256) / 256, 3), bs, 0, stream>>>(offs, bsums, bcur);
  partition_kernel<<<dim3((EE + 255) / 256, 3), bs, 0, stream>>>(e0, e1, e2, bcur, ebuf);
  bucket_sort_kernel<<<dim3(NBUK, 3), bs, 0, stream>>>(ebuf, offs, csr);
  embed_kernel<<<dim3((NN * 64 + 255) / 256), bs, 0, stream>>>(x, embed, hb);

  for (int l = 0; l < 2; ++l) {
    for (int m = 0; m < 3; ++m) {
      agg_kernel<<<dim3((NN + 3) / 4), bs, 0, stream>>>(
          hb, dinv + m * NN, offs + m * (NN + 1), csr + (size_t)m * EE,
          (uint32_hip*)(z + (size_t)m * NN * DD));
      mfma_gemm_kernel<<<dim3((NN + 63) / 64), bs, 0, stream>>>(
          z + (size_t)m * NN * DD, W + ((size_t)l * 3 + m) * DD * DD,
          B + ((size_t)l * 3 + m) * DD, NN);
    }
    mfma_att_kernel<<<dim3((3 * NN + 63) / 64), bs, 0, stream>>>(
        z, aw1 + (size_t)l * DD * DD, ab1 + (size_t)l * DD, aw2 + (size_t)l * DD, wbuf, 3 * NN);
    combine_kernel<<<dim3((NN + 3) / 4), bs, 0, stream>>>(z, wbuf, hb, out, l == 1);
  }
}

// Round 4
// 1003.210 us; speedup vs baseline: 2.4755x; 1.9852x over previous
//
#include <hip/hip_runtime.h>
#include <hip/hip_bf16.h>

#define NN 100000
#define DD 128
#define MM 3
#define EE 1600000
#define NBUK ((NN + 127) / 128)        // 782 dst-buckets per meta-path
#define TILE_E 16384                   // edges per partition tile
#define NTILES ((EE + TILE_E - 1) / TILE_E)  // 98

typedef unsigned int uint32_hip;
typedef short short8 __attribute__((ext_vector_type(8)));
typedef float floatx4 __attribute__((ext_vector_type(4)));

// ---- bf16 helpers (pairs packed in uint) ----
__device__ __forceinline__ float bflo(uint32_hip u) { return __uint_as_float(u << 16); }
__device__ __forceinline__ float bfhi(uint32_hip u) { return __uint_as_float(u & 0xffff0000u); }
__device__ __forceinline__ unsigned short f2bf(float f) {
  union { __hip_bfloat16 b; unsigned short u; } cv;
  cv.b = __float2bfloat16(f);
  return cv.u;
}
__device__ __forceinline__ uint32_hip packbf2(float x, float y) {
  return (uint32_hip)f2bf(x) | ((uint32_hip)f2bf(y) << 16);
}
__device__ __forceinline__ float tanh_apx(float x) {
  float e = __expf(2.0f * x);
  return 1.0f - 2.0f / (e + 1.0f);
}

// ---------- stage 1: per-bucket counts via LDS histogram (no per-edge global atomics) ----------
__global__ void bucket_count_kernel(const int* __restrict__ e0, const int* __restrict__ e1,
                                    const int* __restrict__ e2, int* __restrict__ bcnt) {
  __shared__ int hist[NBUK];
  int m = blockIdx.y, t = threadIdx.x;
  const int* ei = (m == 0) ? e0 : (m == 1) ? e1 : e2;
  const int* dst = ei + EE;
  int beg = blockIdx.x * TILE_E, end = min(beg + TILE_E, EE);
  for (int b = t; b < NBUK; b += 256) hist[b] = 0;
  __syncthreads();
  for (int e = beg + t; e < end; e += 256) atomicAdd(&hist[dst[e] >> 7], 1);
  __syncthreads();
  for (int b = t; b < NBUK; b += 256) {
    int c = hist[b];
    if (c) atomicAdd(&bcnt[m * NBUK + b], c);
  }
}

// ---------- stage 2: scan bucket counts -> bases & cursors ----------
__global__ void bucket_scan_kernel(const int* __restrict__ bcnt, int* __restrict__ bbase,
                                   int* __restrict__ bcur, int* __restrict__ offs) {
  __shared__ int s[1024];
  int m = blockIdx.x, t = threadIdx.x;
  int v = (t < NBUK) ? bcnt[m * NBUK + t] : 0;
  s[t] = v;
  __syncthreads();
  for (int off = 1; off < 1024; off <<= 1) {
    int val = (t >= off) ? s[t - off] : 0;
    __syncthreads();
    s[t] += val;
    __syncthreads();
  }
  if (t < NBUK) {
    int excl = s[t] - v;
    bbase[m * (NBUK + 1) + t] = excl;
    bcur[m * NBUK + t] = excl;
  }
  if (t == 0) {
    bbase[m * (NBUK + 1) + NBUK] = EE;
    offs[m * (NN + 1) + NN] = EE;
  }
}

// ---------- stage 3: tile partition; one global atomic per (WG,bucket) range reservation ----------
__global__ void partition_kernel(const int* __restrict__ e0, const int* __restrict__ e1,
                                 const int* __restrict__ e2, int* __restrict__ bcur,
                                 uint32_hip* __restrict__ ebuf) {
  __shared__ int hist[NBUK];
  int m = blockIdx.y, t = threadIdx.x;
  const int* ei = (m == 0) ? e0 : (m == 1) ? e1 : e2;
  const int* dst = ei + EE;
  int beg = blockIdx.x * TILE_E, end = min(beg + TILE_E, EE);
  for (int b = t; b < NBUK; b += 256) hist[b] = 0;
  __syncthreads();
  for (int e = beg + t; e < end; e += 256) atomicAdd(&hist[dst[e] >> 7], 1);
  __syncthreads();
  for (int b = t; b < NBUK; b += 256) {
    int c = hist[b];
    hist[b] = c ? atomicAdd(&bcur[m * NBUK + b], c) : 0;  // reserve contiguous run
  }
  __syncthreads();
  uint32_hip* eb = ebuf + (size_t)m * EE;
  for (int e = beg + t; e < end; e += 256) {
    int d = dst[e];
    int pos = atomicAdd(&hist[d >> 7], 1);  // LDS cursor
    eb[pos] = (uint32_hip)ei[e] | ((uint32_hip)(d & 127) << 17);
  }
}

// ---------- stage 4: per-bucket sort; also emits per-node offsets + dinv ----------
__global__ void bucket_sort_kernel(const uint32_hip* __restrict__ ebuf,
                                   const int* __restrict__ bbase, int* __restrict__ csr,
                                   int* __restrict__ offs, float* __restrict__ dinv) {
  __shared__ int cnt[128];
  __shared__ int pos[128];
  int m = blockIdx.y, b = blockIdx.x, t = threadIdx.x;
  int beg = bbase[m * (NBUK + 1) + b], end = bbase[m * (NBUK + 1) + b + 1];
  if (t < 128) cnt[t] = 0;
  __syncthreads();
  const uint32_hip* eb = ebuf + (size_t)m * EE;
  for (int e = beg + t; e < end; e += 256) atomicAdd(&cnt[eb[e] >> 17], 1);
  __syncthreads();
  if (t < 128) pos[t] = cnt[t];
  __syncthreads();
  for (int off = 1; off < 128; off <<= 1) {
    int v = (t < 128 && t >= off) ? pos[t - off] : 0;
    __syncthreads();
    if (t < 128) pos[t] += v;
    __syncthreads();
  }
  int node0 = b * 128;
  if (t < 128) {
    int excl = pos[t] - cnt[t];
    pos[t] = beg + excl;  // global start for this node
    int node = node0 + t;
    if (node < NN) {
      offs[m * (NN + 1) + node] = beg + excl;
      dinv[m * NN + node] = rsqrtf((float)(cnt[t] + 1));  // +1 self loop
    }
  }
  __syncthreads();
  int* cs = csr + (size_t)m * EE;
  for (int e = beg + t; e < end; e += 256) {
    uint32_hip p = eb[e];
    int q = atomicAdd(&pos[p >> 17], 1);
    cs[q] = (int)(p & 0x1FFFFu);
  }
}

// ---------- embedding gather -> bf16 h (lives in d_out) ----------
__global__ void embed_kernel(const int* __restrict__ x, const float* __restrict__ tbl,
                             uint32_hip* __restrict__ hb) {
  int i = blockIdx.x * 256 + threadIdx.x;
  if (i < NN * 64) {
    int n = i >> 6;  // 64 uint (=bf16 pairs) per row
    int c = i & 63;
    float2 v = ((const float2*)tbl)[(size_t)x[n] * 64 + c];
    hb[i] = packbf2(v.x, v.y);
  }
}

// ---------- normalized aggregation (bf16 h -> bf16 z), one wave/node ----------
__global__ void agg_kernel(const uint32_hip* __restrict__ h, const float* __restrict__ dinv_m,
                           const int* __restrict__ offs_m, const int* __restrict__ csr_m,
                           uint32_hip* __restrict__ zout) {
  int gtid = blockIdx.x * blockDim.x + threadIdx.x;
  int n = gtid >> 6;
  int lane = gtid & 63;
  if (n >= NN) return;
  float di = dinv_m[n];
  uint32_hip u = h[(size_t)n * 64 + lane];
  float ax = di * bflo(u), ay = di * bfhi(u);
  int e = offs_m[n], end = offs_m[n + 1];
  for (; e + 4 <= end; e += 4) {
    int s0 = csr_m[e], s1 = csr_m[e + 1], s2 = csr_m[e + 2], s3 = csr_m[e + 3];
    float n0 = dinv_m[s0], n1 = dinv_m[s1], n2 = dinv_m[s2], n3 = dinv_m[s3];
    uint32_hip u0 = h[(size_t)s0 * 64 + lane];
    uint32_hip u1 = h[(size_t)s1 * 64 + lane];
    uint32_hip u2 = h[(size_t)s2 * 64 + lane];
    uint32_hip u3 = h[(size_t)s3 * 64 + lane];
    ax = fmaf(n0, bflo(u0), ax); ay = fmaf(n0, bfhi(u0), ay);
    ax = fmaf(n1, bflo(u1), ax); ay = fmaf(n1, bfhi(u1), ay);
    ax = fmaf(n2, bflo(u2), ax); ay = fmaf(n2, bfhi(u2), ay);
    ax = fmaf(n3, bflo(u3), ax); ay = fmaf(n3, bfhi(u3), ay);
  }
  for (; e < end; ++e) {
    int s = csr_m[e];
    float ns = dinv_m[s];
    uint32_hip us = h[(size_t)s * 64 + lane];
    ax = fmaf(ns, bflo(us), ax); ay = fmaf(ns, bfhi(us), ay);
  }
  zout[(size_t)n * 64 + lane] = packbf2(ax * di, ay * di);
}

// ---------- MFMA bf16 GEMM, in-place: Z <- Z @ W + bias ----------
// 16x16x32 layouts (m89/m91): A[m=lane&15][k=quad*8+j]; B[k=quad*8+j][n=lane&15];
// C col=lane&15, row=quad*4+reg.
__global__ __launch_bounds__(256) void mfma_gemm_kernel(unsigned short* __restrict__ Z,
                                                        const float* __restrict__ Wmat,
                                                        const float* __restrict__ bias, int R) {
  __shared__ unsigned short Wt[128 * 136];
  int t = threadIdx.x;
  {
    uint32_hip* Wt_u = (uint32_hip*)Wt;
#pragma unroll
    for (int i = 0; i < 32; ++i) {
      int idx = i * 256 + t;  // 0..8191
      int k2 = idx >> 7;      // k pair index 0..63
      int nn = idx & 127;     // col
      float w0 = Wmat[(2 * k2) * 128 + nn];
      float w1 = Wmat[(2 * k2 + 1) * 128 + nn];
      Wt_u[nn * 68 + k2] = packbf2(w0, w1);
    }
  }
  __syncthreads();
  int wave = t >> 6, lane = t & 63;
  int quad = lane >> 4, ln = lane & 15;
  int rowbase = blockIdx.x * 64 + wave * 16;
  int arow = rowbase + ln;
  int arowc = (arow < R) ? arow : (R - 1);
  const short8* zrow = (const short8*)(Z + (size_t)arowc * 128);
  floatx4 acc[8];
#pragma unroll
  for (int c = 0; c < 8; ++c) acc[c] = (floatx4){0.f, 0.f, 0.f, 0.f};
#pragma unroll
  for (int kt = 0; kt < 4; ++kt) {
    short8 a = zrow[kt * 4 + quad];
#pragma unroll
    for (int c = 0; c < 8; ++c) {
      const short8* bp = (const short8*)(Wt + (c * 16 + ln) * 136 + kt * 32 + quad * 8);
      acc[c] = __builtin_amdgcn_mfma_f32_16x16x32_bf16(a, *bp, acc[c], 0, 0, 0);
    }
  }
#pragma unroll
  for (int c = 0; c < 8; ++c) {
    int col = c * 16 + ln;
    float bs = bias[col];
#pragma unroll
    for (int r = 0; r < 4; ++r) {
      int grow = rowbase + quad * 4 + r;
      if (grow < R) Z[(size_t)grow * 128 + col] = f2bf(acc[c][r] + bs);
    }
  }
}

// ---------- MFMA semantic attention score: w[r] = tanh(Z[r]@W1 + b1) . w2 ----------
__global__ __launch_bounds__(256) void mfma_att_kernel(const unsigned short* __restrict__ Z,
                                                       const float* __restrict__ W1,
                                                       const float* __restrict__ b1,
                                                       const float* __restrict__ w2,
                                                       float* __restrict__ wout, int R) {
  __shared__ unsigned short Wt[128 * 136];
  int t = threadIdx.x;
  {
    uint32_hip* Wt_u = (uint32_hip*)Wt;
#pragma unroll
    for (int i = 0; i < 32; ++i) {
      int idx = i * 256 + t;
      int k2 = idx >> 7;
      int nn = idx & 127;
      float w0 = W1[(2 * k2) * 128 + nn];
      float w1 = W1[(2 * k2 + 1) * 128 + nn];
      Wt_u[nn * 68 + k2] = packbf2(w0, w1);
    }
  }
  __syncthreads();
  int wave = t >> 6, lane = t & 63;
  int quad = lane >> 4, ln = lane & 15;
  int rowbase = blockIdx.x * 64 + wave * 16;
  int arow = rowbase + ln;
  int arowc = (arow < R) ? arow : (R - 1);
  const short8* zrow = (const short8*)(Z + (size_t)arowc * 128);
  floatx4 acc[8];
#pragma unroll
  for (int c = 0; c < 8; ++c) acc[c] = (floatx4){0.f, 0.f, 0.f, 0.f};
#pragma unroll
  for (int kt = 0; kt < 4; ++kt) {
    short8 a = zrow[kt * 4 + quad];
#pragma unroll
    for (int c = 0; c < 8; ++c) {
      const short8* bp = (const short8*)(Wt + (c * 16 + ln) * 136 + kt * 32 + quad * 8);
      acc[c] = __builtin_amdgcn_mfma_f32_16x16x32_bf16(a, *bp, acc[c], 0, 0, 0);
    }
  }
  float rows[4] = {0.f, 0.f, 0.f, 0.f};
#pragma unroll
  for (int c = 0; c < 8; ++c) {
    int col = c * 16 + ln;
    float bb = b1[col];
    float ww = w2[col];
#pragma unroll
    for (int r = 0; r < 4; ++r) rows[r] += tanh_apx(acc[c][r] + bb) * ww;
  }
#pragma unroll
  for (int off = 8; off > 0; off >>= 1) {
#pragma unroll
    for (int r = 0; r < 4; ++r) rows[r] += __shfl_down(rows[r], off);
  }
  if (ln == 0) {
#pragma unroll
    for (int r = 0; r < 4; ++r) {
      int grow = rowbase + quad * 4 + r;
      if (grow < R) wout[grow] = rows[r];
    }
  }
}

// ---------- softmax over M + weighted sum; layer0 -> bf16 h, layer1 -> fp32 log_softmax ----------
__global__ void combine_kernel(const unsigned short* __restrict__ Z,
                               const float* __restrict__ wbuf, uint32_hip* __restrict__ hb,
                               float* __restrict__ fout, int last) {
  int gtid = blockIdx.x * blockDim.x + threadIdx.x;
  int n = gtid >> 6, lane = gtid & 63;
  if (n >= NN) return;
  float w0 = wbuf[n], w1 = wbuf[NN + n], w2v = wbuf[2 * NN + n];
  float mx = fmaxf(w0, fmaxf(w1, w2v));
  float ee0 = __expf(w0 - mx), ee1 = __expf(w1 - mx), ee2 = __expf(w2v - mx);
  float inv = 1.0f / (ee0 + ee1 + ee2);
  float bb0 = ee0 * inv, bb1 = ee1 * inv, bb2 = ee2 * inv;
  const uint32_hip* Zu = (const uint32_hip*)Z;
  size_t base = (size_t)n * 64 + lane;
  uint32_hip p0 = Zu[base];
  uint32_hip p1 = Zu[(size_t)NN * 64 + base];
  uint32_hip p2 = Zu[(size_t)2 * NN * 64 + base];
  float ox = bb0 * bflo(p0) + bb1 * bflo(p1) + bb2 * bflo(p2);
  float oy = bb0 * bfhi(p0) + bb1 * bfhi(p1) + bb2 * bfhi(p2);
  if (!last) {
    hb[base] = packbf2(ox, oy);
  } else {
    float mxv = fmaxf(ox, oy);
#pragma unroll
    for (int off = 32; off > 0; off >>= 1) mxv = fmaxf(mxv, __shfl_xor(mxv, off));
    float s = __expf(ox - mxv) + __expf(oy - mxv);
#pragma unroll
    for (int off = 32; off > 0; off >>= 1) s += __shfl_xor(s, off);
    float lse = mxv + logf(s);
    ((float2*)fout)[base] = make_float2(ox - lse, oy - lse);
  }
}

extern "C" void kernel_launch(void* const* d_in, const int* in_sizes, int n_in,
                              void* d_out, int out_size, void* d_ws, size_t ws_size,
                              hipStream_t stream) {
  const int* x = (const int*)d_in[0];
  const int* e0 = (const int*)d_in[1];
  const int* e1 = (const int*)d_in[2];
  const int* e2 = (const int*)d_in[3];
  const float* embed = (const float*)d_in[4];
  const float* W = (const float*)d_in[5];    // [2][3][128][128]
  const float* B = (const float*)d_in[6];    // [2][3][128]
  const float* aw1 = (const float*)d_in[7];  // [2][128][128]
  const float* ab1 = (const float*)d_in[8];  // [2][128]
  const float* aw2 = (const float*)d_in[9];  // [2][128]
  float* out = (float*)d_out;
  uint32_hip* hb = (uint32_hip*)d_out;  // bf16 h (25.6MB) lives in d_out until final combine

  char* ws = (char*)d_ws;
  size_t off = 0;
  auto alloc = [&](size_t bytes) {
    void* p = ws + off;
    off += (bytes + 255) & ~(size_t)255;
    return p;
  };
  unsigned short* z = (unsigned short*)alloc((size_t)MM * NN * DD * 2);  // bf16, 76.8 MB
  int* csr = (int*)alloc((size_t)MM * EE * 4);                           // 19.2 MB
  int* offs = (int*)alloc((size_t)MM * (NN + 1) * 4);
  float* dinv = (float*)alloc((size_t)MM * NN * 4);
  float* wbuf = (float*)alloc((size_t)MM * NN * 4);
  int* bcnt = (int*)alloc((size_t)MM * NBUK * 4);
  int* bbase = (int*)alloc((size_t)MM * (NBUK + 1) * 4);
  int* bcur = (int*)alloc((size_t)MM * NBUK * 4);
  // ebuf (bucket-partitioned packed edges, 19.2MB) aliases z: z is only written later (agg)
  uint32_hip* ebuf = (uint32_hip*)z;

  hipMemsetAsync(bcnt, 0, (size_t)MM * NBUK * 4, stream);

  dim3 bs(256);
  bucket_count_kernel<<<dim3(NTILES, 3), bs, 0, stream>>>(e0, e1, e2, bcnt);
  bucket_scan_kernel<<<dim3(3), dim3(1024), 0, stream>>>(bcnt, bbase, bcur, offs);
  partition_kernel<<<dim3(NTILES, 3), bs, 0, stream>>>(e0, e1, e2, bcur, ebuf);
  bucket_sort_kernel<<<dim3(NBUK, 3), bs, 0, stream>>>(ebuf, bbase, csr, offs, dinv);
  embed_kernel<<<dim3((NN * 64 + 255) / 256), bs, 0, stream>>>(x, embed, hb);

  for (int l = 0; l < 2; ++l) {
    for (int m = 0; m < 3; ++m) {
      agg_kernel<<<dim3((NN + 3) / 4), bs, 0, stream>>>(
          hb, dinv + m * NN, offs + m * (NN + 1), csr + (size_t)m * EE,
          (uint32_hip*)(z + (size_t)m * NN * DD));
      mfma_gemm_kernel<<<dim3((NN + 63) / 64), bs, 0, stream>>>(
          z + (size_t)m * NN * DD, W + ((size_t)l * 3 + m) * DD * DD,
          B + ((size_t)l * 3 + m) * DD, NN);
    }
    mfma_att_kernel<<<dim3((3 * NN + 63) / 64), bs, 0, stream>>>(
        z, aw1 + (size_t)l * DD * DD, ab1 + (size_t)l * DD, aw2 + (size_t)l * DD, wbuf, 3 * NN);
    combine_kernel<<<dim3((NN + 3) / 4), bs, 0, stream>>>(z, wbuf, hb, out, l == 1);
  }
}